// Round 13
// baseline (11909.705 us; speedup 1.0000x reference)
//
#include <hip/hip_runtime.h>
#include <hip/hip_bf16.h>
#include <cstdint>

#define TT 2048
#define NPRED 512
#define NSTEP (TT + NPRED)   // 2560 phases; phase k: layer0(k) + layer1(k-1)

typedef _Float16 f16;
typedef __attribute__((ext_vector_type(8))) _Float16 f16x8;
typedef __attribute__((ext_vector_type(4))) float f32x4;
typedef unsigned long long u64;

// ws layout (bytes) — all 16B-aligned
#define WB0_OFF   0u          // f16 [16 slice][4 w][10 frag][64 lane][8] = 327680 elem
#define WB1_OFF   655360u     // f16 [16][4][16][64][8] = 524288 elem
#define BIAS0_OFF 1703936u    // f32 [256 j][4 q]
#define BIAS1_OFF 1708032u    // f32 [256][4]
#define HX0_OFF   1712128u    // u64 [3][256 b][128 word] = 786432 B  {epoch<<32 | 2xf16}
#define HX1_OFF   2498560u    // u64 [3][256][128]        = 786432 B
#define PPW_OFF   3284992u    // u64 [2][16 slice][256 b] = 65536 B   {epoch<<32 | f32}

static __device__ __forceinline__ float sigmoidf_(float x) {
    return 1.0f / (1.0f + __expf(-x));
}
static __device__ __forceinline__ u64 lda8(const u64* p) {
    return __hip_atomic_load(p, __ATOMIC_RELAXED, __HIP_MEMORY_SCOPE_AGENT);
}
static __device__ __forceinline__ void sta8(u64* p, u64 v) {
    __hip_atomic_store(p, v, __ATOMIC_RELAXED, __HIP_MEMORY_SCOPE_AGENT);
}
static __device__ __forceinline__ unsigned short f16bits(float x) {
    union { f16 h; unsigned short u; } cv;
    cv.h = (f16)x;
    return cv.u;
}

// ---------------- prep: pack weights as per-wave MFMA B-fragments (f16) + tag-poison ----------------
#define N0_ELEM 327680
#define N1_ELEM 524288
#define WBASE   (N0_ELEM + N1_ELEM + 2048)          // 854016
#define HXW_CNT (3 * 256 * 128)                     // 98304 words per layer
#define PPW_CNT (2 * 16 * 256)                      // 8192 words

__global__ __launch_bounds__(256) void prep_kernel(
    const float* __restrict__ W_ih0, const float* __restrict__ W_hh0,
    const float* __restrict__ b_ih0, const float* __restrict__ b_hh0,
    const float* __restrict__ W_ih1, const float* __restrict__ W_hh1,
    const float* __restrict__ b_ih1, const float* __restrict__ b_hh1,
    f16* __restrict__ WB0, f16* __restrict__ WB1,
    float* __restrict__ bias0P, float* __restrict__ bias1P,
    u64* __restrict__ hx0w, u64* __restrict__ hx1w, u64* __restrict__ ppw)
{
    int idx = blockIdx.x * 256 + threadIdx.x;
    if (idx < N0_ELEM) {
        int e = idx & 7, l = (idx >> 3) & 63;
        int rest = idx >> 9;
        int fr = rest % 10, sw = rest / 10;
        int w = sw & 3, slice = sw >> 2;
        int q = l & 3, jj = (l & 15) >> 2;
        int row = q * 256 + slice * 16 + 4 * w + jj;
        int k = fr * 32 + (l >> 4) * 8 + e;
        float v = (k < 64) ? W_ih0[row * 64 + k] : W_hh0[row * 256 + (k - 64)];
        WB0[idx] = (f16)v;
    } else if (idx < N0_ELEM + N1_ELEM) {
        int i2 = idx - N0_ELEM;
        int e = i2 & 7, l = (i2 >> 3) & 63;
        int rest = i2 >> 9;
        int fr = rest & 15, sw = rest >> 4;
        int w = sw & 3, slice = sw >> 2;
        int q = l & 3, jj = (l & 15) >> 2;
        int row = q * 256 + slice * 16 + 4 * w + jj;
        int k = fr * 32 + (l >> 4) * 8 + e;
        float v = (k < 256) ? W_ih1[row * 256 + k] : W_hh1[row * 256 + (k - 256)];
        WB1[i2] = (f16)v;
    } else if (idx < N0_ELEM + N1_ELEM + 1024) {
        int r = idx - (N0_ELEM + N1_ELEM);
        int j = r >> 2, q = r & 3;
        bias0P[r] = b_ih0[q * 256 + j] + b_hh0[q * 256 + j];
    } else if (idx < N0_ELEM + N1_ELEM + 2048) {
        int r = idx - (N0_ELEM + N1_ELEM + 1024);
        int j = r >> 2, q = r & 3;
        bias1P[r] = b_ih1[q * 256 + j] + b_hh1[q * 256 + j];
    } else if (idx < WBASE + 2 * HXW_CNT) {
        int r = idx - WBASE;
        if (r < HXW_CNT) hx0w[r] = ~0ull;     // invalid epoch tag
        else             hx1w[r - HXW_CNT] = ~0ull;
    } else if (idx < WBASE + 2 * HXW_CNT + PPW_CNT) {
        ppw[idx - (WBASE + 2 * HXW_CNT)] = ~0ull;
    }
}

// ---------------- fused weight-stationary scan + AR: flagless epoch-tagged data sync ----------------
// grid 256 = 16 groups x 16 slices; blockIdx = slice*16 + g.
// Phase k: layer0(k) [frags 0-9] + layer1(k-1) [frags 2-17]; NO cross-block barriers —
// readers poll tagged data words directly.  hx rotation %3 (overwrite-safety proof in journal),
// p_part rotation %2.  A frags: [0-1: x(k) | 2-9: h0(k-1) | 10-17: h1(k-2)].
__global__ __launch_bounds__(256) void fused_kernel(
    const float* __restrict__ input,
    const float* __restrict__ conv_w, const float* __restrict__ conv_b,
    const f16* __restrict__ WB0, const f16* __restrict__ WB1,
    const float* __restrict__ bias0P, const float* __restrict__ bias1P,
    const float* __restrict__ lin_w, const float* __restrict__ lin_b,
    u64* hx0w, u64* hx1w, u64* ppw,
    float* __restrict__ out)
{
    const int t = threadIdx.x;
    const int lane = t & 63, w = t >> 6;
    const int g = blockIdx.x & 15, slice = blockIdx.x >> 4;

    __shared__ __align__(16) f16 Ah[18 * 65 * 8];
    __shared__ __align__(16) float gbuf0[16 * 68 + 4];
    __shared__ __align__(16) float gbuf1[16 * 68 + 4];
    __shared__ float cw_s[64], cb_s[64], lw_s[256];
    __shared__ float p_lds[16];

    // B-fragments (weights) -> registers, resident for whole kernel
    f16x8 B0[10], B1[16];
    {
        const f16* p0 = WB0 + ((size_t)(slice * 4 + w) * 10 * 64 + lane) * 8;
        #pragma unroll
        for (int f = 0; f < 10; ++f) B0[f] = *(const f16x8*)(p0 + f * 512);
        const f16* p1 = WB1 + ((size_t)(slice * 4 + w) * 16 * 64 + lane) * 8;
        #pragma unroll
        for (int f = 0; f < 16; ++f) B1[f] = *(const f16x8*)(p1 + f * 512);
    }

    if (t < 64) { cw_s[t] = conv_w[t]; cb_s[t] = conv_b[t]; }
    lw_s[t] = lin_w[t];

    // zero-init frags 2-17 (h0, h1 regions)
    #pragma unroll
    for (int i = 0; i < 4; ++i) {
        int c = t + 256 * i;
        int d = ((2 + (c >> 6)) * 65 + (c & 63)) * 8;
        f16x8 z = {};
        *(f16x8*)(Ah + d) = z;
    }

    // h-update role
    const int ub = t >> 4, uj = t & 15;
    const int jg = slice * 16 + uj;
    const float4 bs0 = *(const float4*)(bias0P + 4 * jg);
    const float4 bs1 = *(const float4*)(bias1P + 4 * jg);
    float c0 = 0.f, c1 = 0.f;
    const float linb = lin_b[0];

    // readback role
    const int rb = t & 15;       // batch
    const int rest = t >> 4;     // oct base 0..15 (octs rest, rest+16)
    const int bg0 = g * 16;

    __syncthreads();

    //================= scan phases k = 0..TT-1 (NO cross-block barrier) =================
    #pragma unroll 1
    for (int k = 0; k < TT; ++k) {
        // x(k) fill first (input load overlaps polls)
        if (t < 128) {
            int rb2 = t & 15, xoct = t >> 4;
            int k0 = xoct * 8;
            const float* inprow = input + (size_t)(bg0 + rb2) * TT + ((k & 31) << 6);
            float cwv = cw_s[k >> 5], cbv = cb_s[k >> 5];
            f16x8 hv;
            #pragma unroll
            for (int e = 0; e < 8; ++e)
                hv[e] = (f16)fmaxf(inprow[k0 + e] * cwv + cbv, 0.f);
            int d = ((xoct >> 2) * 65 + (rb2 + 16 * (xoct & 3))) * 8;
            *(f16x8*)(Ah + d) = hv;
        }
        // poll h0(k-1) tag k-1, h1(k-2) tag k-2
        if (k >= 1) {
            const u64* s0 = hx0w + (size_t)((k - 1) % 3) * 32768 + (size_t)(bg0 + rb) * 128;
            const u64* s1 = hx1w + (size_t)((k >= 2 ? (k - 2) % 3 : 0)) * 32768 + (size_t)(bg0 + rb) * 128;
            const unsigned tag0 = (unsigned)(k - 1), tag1 = (unsigned)(k - 2);
            const bool need1 = (k >= 2);
            u64 v[16];
            #pragma unroll
            for (int i = 0; i < 4; ++i) v[i]      = lda8(s0 + rest * 4 + i);
            #pragma unroll
            for (int i = 0; i < 4; ++i) v[4 + i]  = lda8(s0 + (rest + 16) * 4 + i);
            if (need1) {
                #pragma unroll
                for (int i = 0; i < 4; ++i) v[8 + i]  = lda8(s1 + rest * 4 + i);
                #pragma unroll
                for (int i = 0; i < 4; ++i) v[12 + i] = lda8(s1 + (rest + 16) * 4 + i);
            }
            for (;;) {
                bool ok = true;
                #pragma unroll
                for (int i = 0; i < 8; ++i) ok &= ((unsigned)(v[i] >> 32) == tag0);
                if (need1) {
                    #pragma unroll
                    for (int i = 8; i < 16; ++i) ok &= ((unsigned)(v[i] >> 32) == tag1);
                }
                if (ok) break;
                __builtin_amdgcn_s_sleep(1);
                #pragma unroll
                for (int i = 0; i < 4; ++i) if ((unsigned)(v[i] >> 32) != tag0) v[i] = lda8(s0 + rest * 4 + i);
                #pragma unroll
                for (int i = 0; i < 4; ++i) if ((unsigned)(v[4+i] >> 32) != tag0) v[4+i] = lda8(s0 + (rest + 16) * 4 + i);
                if (need1) {
                    #pragma unroll
                    for (int i = 0; i < 4; ++i) if ((unsigned)(v[8+i] >> 32) != tag1) v[8+i] = lda8(s1 + rest * 4 + i);
                    #pragma unroll
                    for (int i = 0; i < 4; ++i) if ((unsigned)(v[12+i] >> 32) != tag1) v[12+i] = lda8(s1 + (rest + 16) * 4 + i);
                }
            }
            int oct = rest;
            *(uint4*)(Ah + ((2 + (oct >> 2)) * 65 + (rb + 16 * (oct & 3))) * 8) =
                make_uint4((unsigned)v[0], (unsigned)v[1], (unsigned)v[2], (unsigned)v[3]);
            oct = rest + 16;
            *(uint4*)(Ah + ((2 + (oct >> 2)) * 65 + (rb + 16 * (oct & 3))) * 8) =
                make_uint4((unsigned)v[4], (unsigned)v[5], (unsigned)v[6], (unsigned)v[7]);
            if (need1) {
                oct = rest;
                *(uint4*)(Ah + ((10 + (oct >> 2)) * 65 + (rb + 16 * (oct & 3))) * 8) =
                    make_uint4((unsigned)v[8], (unsigned)v[9], (unsigned)v[10], (unsigned)v[11]);
                oct = rest + 16;
                *(uint4*)(Ah + ((10 + (oct >> 2)) * 65 + (rb + 16 * (oct & 3))) * 8) =
                    make_uint4((unsigned)v[12], (unsigned)v[13], (unsigned)v[14], (unsigned)v[15]);
            }
        }
        __syncthreads();   // Ah ready

        // MFMA both layers off same LDS state
        {
            f32x4 acc = {0.f, 0.f, 0.f, 0.f};
            #pragma unroll
            for (int f = 0; f < 10; ++f) {
                f16x8 a = *(const f16x8*)(Ah + (f * 65 + lane) * 8);
                acc = __builtin_amdgcn_mfma_f32_16x16x32_f16(a, B0[f], acc, 0, 0, 0);
            }
            int rr = w * 16 + (lane & 15);
            int bb = (lane >> 4) * 4;
            #pragma unroll
            for (int qq = 0; qq < 4; ++qq) gbuf0[(bb + qq) * 68 + rr] = acc[qq];
        }
        if (k >= 1) {
            f32x4 acc = {0.f, 0.f, 0.f, 0.f};
            #pragma unroll
            for (int f = 0; f < 16; ++f) {
                f16x8 a = *(const f16x8*)(Ah + ((2 + f) * 65 + lane) * 8);
                acc = __builtin_amdgcn_mfma_f32_16x16x32_f16(a, B1[f], acc, 0, 0, 0);
            }
            int rr = w * 16 + (lane & 15);
            int bb = (lane >> 4) * 4;
            #pragma unroll
            for (int qq = 0; qq < 4; ++qq) gbuf1[(bb + qq) * 68 + rr] = acc[qq];
        }
        __syncthreads();   // gbuf ready; Ah free for next fill

        // updates + tagged publish (no barrier after)
        {
            float4 gv = *(const float4*)(gbuf0 + ub * 68 + uj * 4);
            float gi = gv.x + bs0.x, gf = gv.y + bs0.y, gg = gv.z + bs0.z, go = gv.w + bs0.w;
            float cn = sigmoidf_(gf) * c0 + sigmoidf_(gi) * tanhf(gg);
            float hn = sigmoidf_(go) * tanhf(cn);
            c0 = cn;
            unsigned short hb = f16bits(hn);
            int oth = __shfl_xor((int)hb, 1);
            if (!(uj & 1)) {
                unsigned lo = (unsigned)hb | ((unsigned)(oth & 0xffff) << 16);
                sta8(hx0w + (size_t)(k % 3) * 32768 + (size_t)(bg0 + ub) * 128 + (jg >> 1),
                     ((u64)(unsigned)k << 32) | lo);
            }
        }
        if (k >= 1) {
            float4 gv = *(const float4*)(gbuf1 + ub * 68 + uj * 4);
            float gi = gv.x + bs1.x, gf = gv.y + bs1.y, gg = gv.z + bs1.z, go = gv.w + bs1.w;
            float cn = sigmoidf_(gf) * c1 + sigmoidf_(gi) * tanhf(gg);
            float hn = sigmoidf_(go) * tanhf(cn);
            c1 = cn;
            unsigned short hb = f16bits(hn);
            int oth = __shfl_xor((int)hb, 1);
            if (!(uj & 1)) {
                unsigned lo = (unsigned)hb | ((unsigned)(oth & 0xffff) << 16);
                sta8(hx1w + (size_t)((k - 1) % 3) * 32768 + (size_t)(bg0 + ub) * 128 + (jg >> 1),
                     ((u64)(unsigned)(k - 1) << 32) | lo);
            }
        }
    }

    //================= AR phases k = TT..NSTEP-1 =================
    #pragma unroll 1
    for (int k = TT; k < NSTEP; ++k) {
        // poll h0(k-1) tag k-1 -> frags 2-9 ; h1(k-2) tag k-2 -> frags 10-17
        {
            const u64* s0 = hx0w + (size_t)((k - 1) % 3) * 32768 + (size_t)(bg0 + rb) * 128;
            const u64* s1 = hx1w + (size_t)((k - 2) % 3) * 32768 + (size_t)(bg0 + rb) * 128;
            const unsigned tag0 = (unsigned)(k - 1), tag1 = (unsigned)(k - 2);
            u64 v[16];
            #pragma unroll
            for (int i = 0; i < 4; ++i) v[i]      = lda8(s0 + rest * 4 + i);
            #pragma unroll
            for (int i = 0; i < 4; ++i) v[4 + i]  = lda8(s0 + (rest + 16) * 4 + i);
            #pragma unroll
            for (int i = 0; i < 4; ++i) v[8 + i]  = lda8(s1 + rest * 4 + i);
            #pragma unroll
            for (int i = 0; i < 4; ++i) v[12 + i] = lda8(s1 + (rest + 16) * 4 + i);
            for (;;) {
                bool ok = true;
                #pragma unroll
                for (int i = 0; i < 8; ++i) ok &= ((unsigned)(v[i] >> 32) == tag0);
                #pragma unroll
                for (int i = 8; i < 16; ++i) ok &= ((unsigned)(v[i] >> 32) == tag1);
                if (ok) break;
                __builtin_amdgcn_s_sleep(1);
                #pragma unroll
                for (int i = 0; i < 4; ++i) if ((unsigned)(v[i] >> 32) != tag0) v[i] = lda8(s0 + rest * 4 + i);
                #pragma unroll
                for (int i = 0; i < 4; ++i) if ((unsigned)(v[4+i] >> 32) != tag0) v[4+i] = lda8(s0 + (rest + 16) * 4 + i);
                #pragma unroll
                for (int i = 0; i < 4; ++i) if ((unsigned)(v[8+i] >> 32) != tag1) v[8+i] = lda8(s1 + rest * 4 + i);
                #pragma unroll
                for (int i = 0; i < 4; ++i) if ((unsigned)(v[12+i] >> 32) != tag1) v[12+i] = lda8(s1 + (rest + 16) * 4 + i);
            }
            int oct = rest;
            *(uint4*)(Ah + ((2 + (oct >> 2)) * 65 + (rb + 16 * (oct & 3))) * 8) =
                make_uint4((unsigned)v[0], (unsigned)v[1], (unsigned)v[2], (unsigned)v[3]);
            *(uint4*)(Ah + ((10 + (oct >> 2)) * 65 + (rb + 16 * (oct & 3))) * 8) =
                make_uint4((unsigned)v[8], (unsigned)v[9], (unsigned)v[10], (unsigned)v[11]);
            oct = rest + 16;
            *(uint4*)(Ah + ((2 + (oct >> 2)) * 65 + (rb + 16 * (oct & 3))) * 8) =
                make_uint4((unsigned)v[4], (unsigned)v[5], (unsigned)v[6], (unsigned)v[7]);
            *(uint4*)(Ah + ((10 + (oct >> 2)) * 65 + (rb + 16 * (oct & 3))) * 8) =
                make_uint4((unsigned)v[12], (unsigned)v[13], (unsigned)v[14], (unsigned)v[15]);
        }
        __syncthreads();   // Ah ready

        // layer1(k-1)
        {
            f32x4 acc = {0.f, 0.f, 0.f, 0.f};
            #pragma unroll
            for (int f = 0; f < 16; ++f) {
                f16x8 a = *(const f16x8*)(Ah + ((2 + f) * 65 + lane) * 8);
                acc = __builtin_amdgcn_mfma_f32_16x16x32_f16(a, B1[f], acc, 0, 0, 0);
            }
            int rr = w * 16 + (lane & 15);
            int bb = (lane >> 4) * 4;
            #pragma unroll
            for (int qq = 0; qq < 4; ++qq) gbuf1[(bb + qq) * 68 + rr] = acc[qq];
        }
        __syncthreads();   // gbuf1 ready

        // h1(k-1) update + tagged publish + tagged p-partials
        {
            float4 gv = *(const float4*)(gbuf1 + ub * 68 + uj * 4);
            float gi = gv.x + bs1.x, gf = gv.y + bs1.y, gg = gv.z + bs1.z, go = gv.w + bs1.w;
            float cn = sigmoidf_(gf) * c1 + sigmoidf_(gi) * tanhf(gg);
            float hn = sigmoidf_(go) * tanhf(cn);
            c1 = cn;
            unsigned short hb = f16bits(hn);
            int oth = __shfl_xor((int)hb, 1);
            if (!(uj & 1)) {
                unsigned lo = (unsigned)hb | ((unsigned)(oth & 0xffff) << 16);
                sta8(hx1w + (size_t)((k - 1) % 3) * 32768 + (size_t)(bg0 + ub) * 128 + (jg >> 1),
                     ((u64)(unsigned)(k - 1) << 32) | lo);
            }
            float pp = hn * lw_s[jg];
            pp += __shfl_xor(pp, 1);
            pp += __shfl_xor(pp, 2);
            pp += __shfl_xor(pp, 4);
            pp += __shfl_xor(pp, 8);
            if (uj == 0)
                sta8(ppw + (size_t)(k & 1) * 4096 + (size_t)slice * 256 + (bg0 + ub),
                     ((u64)(unsigned)k << 32) | (u64)__float_as_uint(pp));
        }

        // p = sum of 16 tagged slice partials (deterministic order)
        if (t < 16) {
            const u64* pb = ppw + (size_t)(k & 1) * 4096;
            u64 pv[16];
            #pragma unroll
            for (int sl = 0; sl < 16; ++sl) pv[sl] = lda8(pb + sl * 256 + bg0 + t);
            for (;;) {
                bool ok = true;
                #pragma unroll
                for (int sl = 0; sl < 16; ++sl) ok &= ((unsigned)(pv[sl] >> 32) == (unsigned)k);
                if (ok) break;
                __builtin_amdgcn_s_sleep(1);
                #pragma unroll
                for (int sl = 0; sl < 16; ++sl)
                    if ((unsigned)(pv[sl] >> 32) != (unsigned)k) pv[sl] = lda8(pb + sl * 256 + bg0 + t);
            }
            float ps = 0.f;
            #pragma unroll
            for (int sl = 0; sl < 16; ++sl) ps += __uint_as_float((unsigned)pv[sl]);
            float p = ps + linb;
            p_lds[t] = p;
            if (slice == 0) out[(size_t)(bg0 + t) * NPRED + (k - TT)] = p;
        }
        __syncthreads();   // p_lds visible; gbuf1 reads done
        if (k == NSTEP - 1) break;

        // x(k) = relu(p*cw+cb)
        if (t < 128) {
            int rb2 = t & 15, xoct = t >> 4;
            int k0 = xoct * 8;
            float p = p_lds[rb2];
            f16x8 hv;
            #pragma unroll
            for (int e = 0; e < 8; ++e)
                hv[e] = (f16)fmaxf(p * cw_s[k0 + e] + cb_s[k0 + e], 0.f);
            int d = ((xoct >> 2) * 65 + (rb2 + 16 * (xoct & 3))) * 8;
            *(f16x8*)(Ah + d) = hv;
        }
        __syncthreads();   // x ready

        // layer0(k)
        {
            f32x4 acc = {0.f, 0.f, 0.f, 0.f};
            #pragma unroll
            for (int f = 0; f < 10; ++f) {
                f16x8 a = *(const f16x8*)(Ah + (f * 65 + lane) * 8);
                acc = __builtin_amdgcn_mfma_f32_16x16x32_f16(a, B0[f], acc, 0, 0, 0);
            }
            int rr = w * 16 + (lane & 15);
            int bb = (lane >> 4) * 4;
            #pragma unroll
            for (int qq = 0; qq < 4; ++qq) gbuf0[(bb + qq) * 68 + rr] = acc[qq];
        }
        __syncthreads();   // gbuf0 ready
        {
            float4 gv = *(const float4*)(gbuf0 + ub * 68 + uj * 4);
            float gi = gv.x + bs0.x, gf = gv.y + bs0.y, gg = gv.z + bs0.z, go = gv.w + bs0.w;
            float cn = sigmoidf_(gf) * c0 + sigmoidf_(gi) * tanhf(gg);
            float hn = sigmoidf_(go) * tanhf(cn);
            c0 = cn;
            unsigned short hb = f16bits(hn);
            int oth = __shfl_xor((int)hb, 1);
            if (!(uj & 1)) {
                unsigned lo = (unsigned)hb | ((unsigned)(oth & 0xffff) << 16);
                sta8(hx0w + (size_t)(k % 3) * 32768 + (size_t)(bg0 + ub) * 128 + (jg >> 1),
                     ((u64)(unsigned)k << 32) | lo);
            }
        }
    }
}

extern "C" void kernel_launch(void* const* d_in, const int* in_sizes, int n_in,
                              void* d_out, int out_size, void* d_ws, size_t ws_size,
                              hipStream_t stream) {
    const float* input  = (const float*)d_in[0];
    const float* conv_w = (const float*)d_in[1];
    const float* conv_b = (const float*)d_in[2];
    const float* W_ih0  = (const float*)d_in[3];
    const float* W_hh0  = (const float*)d_in[4];
    const float* b_ih0  = (const float*)d_in[5];
    const float* b_hh0  = (const float*)d_in[6];
    const float* W_ih1  = (const float*)d_in[7];
    const float* W_hh1  = (const float*)d_in[8];
    const float* b_ih1  = (const float*)d_in[9];
    const float* b_hh1  = (const float*)d_in[10];
    const float* lin_w  = (const float*)d_in[11];
    const float* lin_b  = (const float*)d_in[12];
    float* out = (float*)d_out;

    uint8_t* ws = (uint8_t*)d_ws;
    f16* WB0 = (f16*)(ws + WB0_OFF);
    f16* WB1 = (f16*)(ws + WB1_OFF);
    float* bias0P = (float*)(ws + BIAS0_OFF);
    float* bias1P = (float*)(ws + BIAS1_OFF);
    u64* hx0w = (u64*)(ws + HX0_OFF);
    u64* hx1w = (u64*)(ws + HX1_OFF);
    u64* ppw  = (u64*)(ws + PPW_OFF);

    // 854016 + 196608 + 8192 = 1058816 elems -> 4136 blocks of 256
    prep_kernel<<<4136, 256, 0, stream>>>(W_ih0, W_hh0, b_ih0, b_hh0,
                                          W_ih1, W_hh1, b_ih1, b_hh1,
                                          WB0, WB1, bias0P, bias1P,
                                          hx0w, hx1w, ppw);

    fused_kernel<<<256, 256, 0, stream>>>(input, conv_w, conv_b,
                                          WB0, WB1, bias0P, bias1P,
                                          lin_w, lin_b, hx0w, hx1w, ppw, out);
}